// Round 7
// baseline (234.646 us; speedup 1.0000x reference)
//
#include <hip/hip_runtime.h>

// GCN 2-layer forward (Hu et al. mol-GNN variant) — coarse-bin coalesced scatter +
// all-LDS bucket sort build, bf16+int8 links, MFMA GEMM, split-list aggregate.
//
//   dis[n] = 1/sqrt(1 + outdeg(n))
//   per layer: h = X@W.T + b; store bf16 rows (self term + next GEMM input) AND
//              per-row-scaled int8 rows (64 B — edge-gather path).
//   out[n] = dis[n]^2*(h_bf16[n]+emb_self) + sum_{e: dst=n} dis[s]*dis[n]*(h_q8[s]*sc[s]+emb_e)
//
// Measured facts / ledger:
//  - R2: VALU GEMM 59us -> MFMA (16x16x32 bf16): gemm off top-5.
//  - R3: isolated 1-4B scatter stores 45us -> LDS counting sort + coalesced runs.
//  - R4/R5/R6: bin-granularity experiments all land 221-231us; R6's 44.5KB scatter
//    LDS cut the GEMM-rider occupancy 6->3 blocks/CU (riders inherit the host
//    kernel's static LDS) — this round scatter LDS back to 24KB (CHUNK=2048).
//  - Pipeline is ~6x above the ~35us byte roofline -> latency-bound; the two
//    aggregates are the largest remaining cost. This round: 16 lanes/node, each
//    8-lane half walks a contiguous half of the edge list 4-wide (8 gathers in
//    flight/node, halved serial chain + divergence), shfl_xor(8) combine.
// Payload: src(17b) | emb(5b)<<17 | dstLow10(10b)<<22 (exactly 32 bits).

#define THREADS 256
#define MAXNB 128    // 1024-node coarse bins, N <= 131072
#define BCAP 12288   // per-bin edge capacity (mean 10204 @ E=1M,N=100k; +20 sigma)
#define CHUNK 2048   // edges per scatter block
#define GEMM_SMEM_BYTES (64 * 68 * 4)
// scatter LDS: Wv[2048]u32 + SD[2048]u32 + DB[2048]u8 + SDB[2048]u8 + 7*128 ints
#define SC_SMEM (CHUNK * 4 * 2 + CHUNK * 2 + 7 * MAXNB * 4)  // 24064
// build LDS: cnt[1024] + cur[1024] + s[256] + stg[BCAP] ints
#define BD_SMEM ((1024 + 1024 + 256 + BCAP) * 4)  // 58368

typedef __attribute__((ext_vector_type(8))) short bf16x8;
typedef __attribute__((ext_vector_type(4))) float f32x4;

__device__ __forceinline__ float bflo(unsigned int v) { return __uint_as_float(v << 16); }
__device__ __forceinline__ float bfhi(unsigned int v) { return __uint_as_float(v & 0xFFFF0000u); }
__device__ __forceinline__ unsigned short f2bf(float f) {  // round-to-nearest-even
    unsigned int u = __float_as_uint(f);
    return (unsigned short)((u + 0x7FFFu + ((u >> 16) & 1u)) >> 16);
}
__device__ __forceinline__ int sb(unsigned int w, int j) {  // signed byte j of word
    return (int)(w << (24 - 8 * j)) >> 24;
}

// ---- GEMM tile body (MFMA): Hb = bf16(X @ W.T + B), Hq = int8 per-row-quant.
// 4 waves; wave w owns rows [16w,16w+16) of the 64-row tile, all 64 cols.
// A: lane l&15 = row, 8 contiguous k at 8*(l>>4) (+32 for kstep 1).
// B: lane l&15 = col (W row 16n+(l&15)), same k packing -> k-mapping cancels.
// C/D (m89-verified): col = lane&15, row(within 16-tile) = 4*(lane>>4)+reg.
template <bool XBF16>
__device__ __forceinline__ void gemm64_body(int tile, const void* __restrict__ Xv,
                                            const float* __restrict__ W,
                                            const float* __restrict__ B,
                                            unsigned short* __restrict__ Hb,
                                            unsigned char* __restrict__ Hq,
                                            float2* __restrict__ dsc, int N,
                                            float (*smem)[68]) {
    int t = threadIdx.x;
    int lane = t & 63;
    int wave = __builtin_amdgcn_readfirstlane(t >> 6);
    int l15 = lane & 15;
    int lk = lane >> 4;  // k-chunk id 0..3
    int arow = tile * 64 + wave * 16 + l15;

    bf16x8 a0, a1;
    if (arow < N) {
        if (XBF16) {
            const unsigned short* xp = (const unsigned short*)Xv + (size_t)arow * 64 + 8 * lk;
            a0 = *(const bf16x8*)xp;
            a1 = *(const bf16x8*)(xp + 32);
        } else {
            const float* xp = (const float*)Xv + (size_t)arow * 64 + 8 * lk;
            float4 v0 = *(const float4*)xp;
            float4 v1 = *(const float4*)(xp + 4);
            float4 v2 = *(const float4*)(xp + 32);
            float4 v3 = *(const float4*)(xp + 36);
            a0[0] = (short)f2bf(v0.x); a0[1] = (short)f2bf(v0.y);
            a0[2] = (short)f2bf(v0.z); a0[3] = (short)f2bf(v0.w);
            a0[4] = (short)f2bf(v1.x); a0[5] = (short)f2bf(v1.y);
            a0[6] = (short)f2bf(v1.z); a0[7] = (short)f2bf(v1.w);
            a1[0] = (short)f2bf(v2.x); a1[1] = (short)f2bf(v2.y);
            a1[2] = (short)f2bf(v2.z); a1[3] = (short)f2bf(v2.w);
            a1[4] = (short)f2bf(v3.x); a1[5] = (short)f2bf(v3.y);
            a1[6] = (short)f2bf(v3.z); a1[7] = (short)f2bf(v3.w);
        }
    } else {
#pragma unroll
        for (int e = 0; e < 8; ++e) { a0[e] = 0; a1[e] = 0; }
    }

    bf16x8 bfr[4][2];
#pragma unroll
    for (int n = 0; n < 4; ++n) {
        const float* wp = W + (size_t)(16 * n + l15) * 64 + 8 * lk;
#pragma unroll
        for (int ks = 0; ks < 2; ++ks) {
            float4 u0 = *(const float4*)(wp + 32 * ks);
            float4 u1 = *(const float4*)(wp + 32 * ks + 4);
            bf16x8 bb;
            bb[0] = (short)f2bf(u0.x); bb[1] = (short)f2bf(u0.y);
            bb[2] = (short)f2bf(u0.z); bb[3] = (short)f2bf(u0.w);
            bb[4] = (short)f2bf(u1.x); bb[5] = (short)f2bf(u1.y);
            bb[6] = (short)f2bf(u1.z); bb[7] = (short)f2bf(u1.w);
            bfr[n][ks] = bb;
        }
    }

    f32x4 acc[4];
#pragma unroll
    for (int n = 0; n < 4; ++n) {
        f32x4 z = {0.0f, 0.0f, 0.0f, 0.0f};
        z = __builtin_amdgcn_mfma_f32_16x16x32_bf16(a0, bfr[n][0], z, 0, 0, 0);
        acc[n] = __builtin_amdgcn_mfma_f32_16x16x32_bf16(a1, bfr[n][1], z, 0, 0, 0);
    }

    // bias + stage to LDS: out row (tile-local) = 16*wave + 4*lk + reg, col = 16n+l15.
#pragma unroll
    for (int n = 0; n < 4; ++n) {
        float bv = B[16 * n + l15];
        int col = 16 * n + l15;
#pragma unroll
        for (int r = 0; r < 4; ++r)
            smem[16 * wave + 4 * lk + r][col] = acc[n][r] + bv;
    }
    __syncthreads();

    // writeout: 512 row-groups of 8 floats; 8 contiguous lanes own one row.
#pragma unroll
    for (int i = 0; i < 2; ++i) {
        int idx = t + i * THREADS;
        int r = idx >> 3;
        int c8 = (idx & 7) << 3;
        int grow = tile * 64 + r;
        float4 va = *(const float4*)(&smem[r][c8]);
        float4 vb = *(const float4*)(&smem[r][c8 + 4]);
        float v[8] = {va.x, va.y, va.z, va.w, vb.x, vb.y, vb.z, vb.w};
        float m = fabsf(v[0]);
#pragma unroll
        for (int j = 1; j < 8; ++j) m = fmaxf(m, fabsf(v[j]));
        m = fmaxf(m, __shfl_xor(m, 1));  // 8 lanes/row are contiguous
        m = fmaxf(m, __shfl_xor(m, 2));
        m = fmaxf(m, __shfl_xor(m, 4));
        if (grow < N) {
            uint4 o;
            o.x = (unsigned)f2bf(v[0]) | ((unsigned)f2bf(v[1]) << 16);
            o.y = (unsigned)f2bf(v[2]) | ((unsigned)f2bf(v[3]) << 16);
            o.z = (unsigned)f2bf(v[4]) | ((unsigned)f2bf(v[5]) << 16);
            o.w = (unsigned)f2bf(v[6]) | ((unsigned)f2bf(v[7]) << 16);
            *(uint4*)(Hb + (size_t)grow * 64 + c8) = o;
            float inv = m > 0.0f ? 127.0f / m : 0.0f;
            int q[8];
#pragma unroll
            for (int j = 0; j < 8; ++j) q[j] = __float2int_rn(v[j] * inv);
            uint2 qp;
            qp.x = (unsigned)(q[0] & 255) | ((unsigned)(q[1] & 255) << 8) |
                   ((unsigned)(q[2] & 255) << 16) | ((unsigned)(q[3] & 255) << 24);
            qp.y = (unsigned)(q[4] & 255) | ((unsigned)(q[5] & 255) << 8) |
                   ((unsigned)(q[6] & 255) << 16) | ((unsigned)(q[7] & 255) << 24);
            *(uint2*)(Hq + (size_t)grow * 64 + c8) = qp;
            if ((idx & 7) == 0) dsc[grow].y = m * (1.0f / 127.0f);
        }
    }
}

// ---- K0: zero the bucket cursors (block 0) + gemm1 tiles (blocks 1..) ----
__global__ __launch_bounds__(THREADS) void zero_gemm_kernel(
    int* __restrict__ gcur, int ncur, const float* __restrict__ X,
    const float* __restrict__ W1, const float* __restrict__ B1,
    unsigned short* __restrict__ Hb, unsigned char* __restrict__ Hq,
    float2* __restrict__ dsc, int N, int tile0) {
    __shared__ __align__(16) char sh[GEMM_SMEM_BYTES];
    int b = blockIdx.x;
    if (b == 0) {
        for (int i = threadIdx.x; i < ncur; i += THREADS) gcur[i] = 0;
        return;
    }
    gemm64_body<false>(tile0 + b - 1, X, W1, B1, Hb, Hq, dsc, N, (float(*)[68])sh);
}

// ---- K1: LDS-sorted scatter into NB coarse bins (1024 nodes each). Per block:
// stage CHUNK edges + bin histograms; one global-atomic reservation per touched bin;
// in-LDS counting sort by dst-bin (payD) and src-bin (payS); coalesced writeout in
// ~21-edge (84 B) runs. 24KB LDS -> 6 blocks/CU for the gemm riders too.
__global__ __launch_bounds__(THREADS) void scatter_kernel(
    const int* __restrict__ src, const int* __restrict__ dst, const int* __restrict__ attr,
    int* __restrict__ gcurS, int* __restrict__ gcurD, unsigned short* __restrict__ payS,
    unsigned int* __restrict__ payD, int E, int NB, int SCB,
    const float* __restrict__ X, const float* __restrict__ W1, const float* __restrict__ B1,
    unsigned short* __restrict__ Hb, unsigned char* __restrict__ Hq,
    float2* __restrict__ dsc, int N, int tile0) {
    __shared__ __align__(16) char sh[SC_SMEM];
    int b = blockIdx.x;
    if (b >= SCB) {
        gemm64_body<false>(tile0 + b - SCB, X, W1, B1, Hb, Hq, dsc, N, (float(*)[68])sh);
        return;
    }
    unsigned int* Wv = (unsigned int*)sh;                // [CHUNK]
    unsigned int* SD = Wv + CHUNK;                       // [CHUNK] dst-sorted words
    unsigned char* DB = (unsigned char*)(SD + CHUNK);    // [CHUNK] dst bin
    unsigned char* SDB = DB + CHUNK;                     // [CHUNK] sorted dst bin
    int* hD = (int*)(SDB + CHUNK);
    int* hS = hD + MAXNB;
    int* mapD = hS + MAXNB;
    int* mapS = mapD + MAXNB;
    int* curD = mapS + MAXNB;
    int* curS = curD + MAXNB;
    int* scn = curS + MAXNB;                             // [128]
    unsigned short* SS = (unsigned short*)Wv;            // reuse after place-D
    unsigned char* SSB = DB;                             // reuse after place-D

    int t = threadIdx.x;
    if (t < MAXNB) { hD[t] = 0; hS[t] = 0; }
    __syncthreads();

    int lo = b * CHUNK, hi = min(E, lo + CHUNK);
    int nch = hi - lo;
    const int2* ap = (const int2*)attr;
    for (int li = t; li < nch; li += THREADS) {
        int i = lo + li;
        int sv = src[i], dv = dst[i];
        int2 a = ap[i];
        Wv[li] = (unsigned int)sv | ((unsigned int)(a.x * 3 + a.y) << 17) |
                 ((unsigned int)(dv & 1023) << 22);
        DB[li] = (unsigned char)(dv >> 10);
        atomicAdd(&hD[dv >> 10], 1);  // LDS atomic
        atomicAdd(&hS[sv >> 10], 1);  // LDS atomic
    }
    __syncthreads();

    // reserve global ranges (one atomic per touched bin per stream)
    if (t < NB) {
        int h = hD[t];
        int r = h ? atomicAdd(&gcurD[t], h) : 0;  // global atomic, low contention
        mapD[t] = t * BCAP + r;
        int h2 = hS[t];
        int r2 = h2 ? atomicAdd(&gcurS[t], h2) : 0;
        mapS[t] = t * BCAP + r2;
    }
    // exclusive scan of hD over bins -> local run starts; adjust map
    if (t < MAXNB) scn[t] = (t < NB) ? hD[t] : 0;
    __syncthreads();
    for (int d = 1; d < MAXNB; d <<= 1) {
        int a = (t >= d && t < MAXNB) ? scn[t - d] : 0;
        __syncthreads();
        if (t < MAXNB) scn[t] += a;
        __syncthreads();
    }
    if (t < NB) {
        int excl = scn[t] - hD[t];
        curD[t] = excl;
        mapD[t] -= excl;
    }
    __syncthreads();
    if (t < MAXNB) scn[t] = (t < NB) ? hS[t] : 0;
    __syncthreads();
    for (int d = 1; d < MAXNB; d <<= 1) {
        int a = (t >= d && t < MAXNB) ? scn[t - d] : 0;
        __syncthreads();
        if (t < MAXNB) scn[t] += a;
        __syncthreads();
    }
    if (t < NB) {
        int excl = scn[t] - hS[t];
        curS[t] = excl;
        mapS[t] -= excl;
    }
    __syncthreads();

    // place by dst-bin (consumes Wv/DB into SD/SDB)
    for (int li = t; li < nch; li += THREADS) {
        int k = DB[li];
        int p = atomicAdd(&curD[k], 1);  // LDS atomic
        SD[p] = Wv[li];
        SDB[p] = (unsigned char)k;
    }
    __syncthreads();

    // place by src-bin (sources from SD; reuses Wv region as SS, DB as SSB)
    for (int li = t; li < nch; li += THREADS) {
        int val = (int)(SD[li] & 0x1FFFFu);
        int k = val >> 10;
        int p = atomicAdd(&curS[k], 1);  // LDS atomic
        SS[p] = (unsigned short)(val & 1023);
        SSB[p] = (unsigned char)k;
    }
    __syncthreads();

    // linear coalesced writeout (runs of ~CHUNK/NB = 21 edges per bin)
    for (int li = t; li < nch; li += THREADS) {
        payD[mapD[SDB[li]] + li] = SD[li];
        payS[mapS[SSB[li]] + li] = SS[li];
    }
}

// ---- K2: per 1024-node bin. Blocks [0,NB): out-degree hist (all-LDS) -> dsc.x.
// Blocks [NB,2NB): counting sort of the bin's dst edges staged ENTIRELY in LDS,
// then one linear coalesced writeout -> sorted + row_ptr/cnt.
__global__ __launch_bounds__(THREADS) void build_kernel(
    const unsigned short* __restrict__ payS, const unsigned int* __restrict__ payD,
    const int* __restrict__ gcurS, const int* __restrict__ gcurD,
    unsigned int* __restrict__ sorted, int* __restrict__ row_ptr, int* __restrict__ cnt_out,
    int NB, float2* __restrict__ dsc, int N) {
    __shared__ __align__(16) char sh[BD_SMEM];
    int* cnt = (int*)sh;             // [1024]
    int* cur = cnt + 1024;           // [1024]
    int* s = cur + 1024;             // [256]
    unsigned int* stg = (unsigned int*)(s + 256);  // [BCAP]
    int t = threadIdx.x;
    int b = blockIdx.x;
    if (b < NB) {
        // phase A: out-degree for bin b
        int k = b;
        for (int i = t; i < 1024; i += THREADS) cnt[i] = 0;
        __syncthreads();
        int n = gcurS[k], off = k * BCAP;
        for (int i = t; i < n; i += THREADS) atomicAdd(&cnt[payS[off + i]], 1);  // LDS atomic
        __syncthreads();
        for (int i = t; i < 1024; i += THREADS) {
            int node = k * 1024 + i;
            if (node < N) dsc[node].x = 1.0f / sqrtf(1.0f + (float)cnt[i]);
        }
    } else {
        // phase B: dst counting sort for bin b-NB, staged in LDS
        int k = b - NB;
        for (int i = t; i < 1024; i += THREADS) cnt[i] = 0;
        __syncthreads();
        int ecnt = gcurD[k], eoff = k * BCAP;
        for (int i = t; i < ecnt; i += THREADS)
            atomicAdd(&cnt[(payD[eoff + i] >> 22) & 1023], 1);  // LDS atomic
        __syncthreads();
        int base4 = t * 4;
        int v0 = cnt[base4], v1 = cnt[base4 + 1], v2 = cnt[base4 + 2], v3 = cnt[base4 + 3];
        s[t] = v0 + v1 + v2 + v3;
        __syncthreads();
        for (int d = 1; d < THREADS; d <<= 1) {
            int a = (t >= d) ? s[t - d] : 0;
            __syncthreads();
            s[t] += a;
            __syncthreads();
        }
        int off = (t == 0) ? 0 : s[t - 1];
        int o0 = off, o1 = off + v0, o2 = o1 + v1, o3 = o2 + v2;
        __syncthreads();
        cur[base4] = o0;
        cur[base4 + 1] = o1;
        cur[base4 + 2] = o2;
        cur[base4 + 3] = o3;
#pragma unroll
        for (int j = 0; j < 4; ++j) {
            int node = k * 1024 + base4 + j;
            if (node < N) {
                row_ptr[node] = eoff + ((j == 0) ? o0 : (j == 1) ? o1 : (j == 2) ? o2 : o3);
                cnt_out[node] = (j == 0) ? v0 : (j == 1) ? v1 : (j == 2) ? v2 : v3;
            }
        }
        __syncthreads();
        for (int i = t; i < ecnt; i += THREADS) {
            unsigned int u = payD[eoff + i];  // L2-warm re-read
            int p = atomicAdd(&cur[(u >> 22) & 1023], 1);  // LDS atomic
            stg[p] = u & 0x3FFFFFu;                        // keep src | emb<<17
        }
        __syncthreads();
        for (int i = t; i < ecnt; i += THREADS) sorted[eoff + i] = stg[i];  // coalesced
    }
}

// ---- standalone GEMM wrapper (layer 2) ----
template <bool XBF16>
__global__ __launch_bounds__(THREADS) void gemm64_kernel(const void* __restrict__ Xv,
                                                         const float* __restrict__ W,
                                                         const float* __restrict__ B,
                                                         unsigned short* __restrict__ Hb,
                                                         unsigned char* __restrict__ Hq,
                                                         float2* __restrict__ dsc, int N) {
    __shared__ __align__(16) char sh[GEMM_SMEM_BYTES];
    gemm64_body<XBF16>(blockIdx.x, Xv, W, B, Hb, Hq, dsc, N, (float(*)[68])sh);
}

// ---- aggregate: 16 lanes/node (two 8-lane halves, each walks a CONTIGUOUS half of
// the edge list 4-wide with dual accumulators -> 8 gathers in flight per node,
// halved serial chain + divergence tail). shfl_xor(8) combines the halves.
__device__ __forceinline__ void edge_acc(unsigned int u, float dn,
                                         const float2* __restrict__ dsc,
                                         const unsigned char* __restrict__ Hq, int c,
                                         const float (*embc)[64], float acc[8]) {
    int s0 = u & 0x1FFFF;
    int e0 = (u >> 17) & 31;
    float2 ds = dsc[s0];
    uint2 q = *(const uint2*)(Hq + (size_t)s0 * 64 + c);
    float w = ds.x * dn, ws = w * ds.y;
    float4 ea = *(const float4*)(&embc[e0][c]);
    float4 eb = *(const float4*)(&embc[e0][c + 4]);
    acc[0] = fmaf(ws, (float)sb(q.x, 0), fmaf(w, ea.x, acc[0]));
    acc[1] = fmaf(ws, (float)sb(q.x, 1), fmaf(w, ea.y, acc[1]));
    acc[2] = fmaf(ws, (float)sb(q.x, 2), fmaf(w, ea.z, acc[2]));
    acc[3] = fmaf(ws, (float)sb(q.x, 3), fmaf(w, ea.w, acc[3]));
    acc[4] = fmaf(ws, (float)sb(q.y, 0), fmaf(w, eb.x, acc[4]));
    acc[5] = fmaf(ws, (float)sb(q.y, 1), fmaf(w, eb.y, acc[5]));
    acc[6] = fmaf(ws, (float)sb(q.y, 2), fmaf(w, eb.z, acc[6]));
    acc[7] = fmaf(ws, (float)sb(q.y, 3), fmaf(w, eb.w, acc[7]));
}

template <bool RELU_BF16_OUT>
__global__ __launch_bounds__(THREADS) void aggregate_kernel(
    const unsigned short* __restrict__ Hb, const unsigned char* __restrict__ Hq,
    const float2* __restrict__ dsc, const float* __restrict__ ebond,
    const float* __restrict__ edir, const int* __restrict__ row_ptr,
    const int* __restrict__ cnt, const unsigned int* __restrict__ entries,
    void* __restrict__ outv, int N) {
    __shared__ float embc[18][64];
    int t = threadIdx.x;
    for (int i = t; i < 18 * 64; i += THREADS) {
        int row = i >> 6, c = i & 63;
        embc[row][c] = ebond[(row / 3) * 64 + c] + edir[(row % 3) * 64 + c];
    }
    __syncthreads();

    int n = blockIdx.x * 16 + (t >> 4);
    if (n >= N) return;
    int half = (t >> 3) & 1;
    int c = (t & 7) << 3;

    float dn = dsc[n].x;
    float accA[8], accB[8];
#pragma unroll
    for (int j = 0; j < 8; ++j) { accA[j] = 0.0f; accB[j] = 0.0f; }

    if (half == 0) {  // self term on half 0 only
        uint4 hv = *(const uint4*)(Hb + (size_t)n * 64 + c);
        float4 ea = *(const float4*)(&embc[12][c]);  // self-loop: bt=4, bd=0 -> idx 12
        float4 eb = *(const float4*)(&embc[12][c + 4]);
        float nrm = dn * dn;
        accA[0] = nrm * (bflo(hv.x) + ea.x);
        accA[1] = nrm * (bfhi(hv.x) + ea.y);
        accA[2] = nrm * (bflo(hv.y) + ea.z);
        accA[3] = nrm * (bfhi(hv.y) + ea.w);
        accA[4] = nrm * (bflo(hv.z) + eb.x);
        accA[5] = nrm * (bfhi(hv.z) + eb.y);
        accA[6] = nrm * (bflo(hv.w) + eb.z);
        accA[7] = nrm * (bfhi(hv.w) + eb.w);
    }

    int rp = row_ptr[n];
    int cn = cnt[n];
    int hA = (cn + 1) >> 1;                 // half 0: [rp, rp+hA), half 1: [rp+hA, rp+cn)
    int p = rp + (half ? hA : 0);
    int end = rp + (half ? cn : hA);
    const float(*ec)[64] = (const float(*)[64])embc;
    for (; p + 3 < end; p += 4) {
        unsigned int u0 = entries[p];
        unsigned int u1 = entries[p + 1];
        unsigned int u2 = entries[p + 2];
        unsigned int u3 = entries[p + 3];
        edge_acc(u0, dn, dsc, Hq, c, ec, accA);
        edge_acc(u1, dn, dsc, Hq, c, ec, accB);
        edge_acc(u2, dn, dsc, Hq, c, ec, accA);
        edge_acc(u3, dn, dsc, Hq, c, ec, accB);
    }
    for (; p < end; ++p) edge_acc(entries[p], dn, dsc, Hq, c, ec, accA);

    float o[8];
#pragma unroll
    for (int j = 0; j < 8; ++j) {
        float v = accA[j] + accB[j];
        v += __shfl_xor(v, 8);  // combine the two halves (lanes l and l^8, same node)
        o[j] = v;
    }
    if (half != 0) return;

    if (RELU_BF16_OUT) {
        unsigned short* ob = (unsigned short*)outv;
        uint4 ov;
        ov.x = (unsigned)f2bf(fmaxf(o[0], 0.0f)) | ((unsigned)f2bf(fmaxf(o[1], 0.0f)) << 16);
        ov.y = (unsigned)f2bf(fmaxf(o[2], 0.0f)) | ((unsigned)f2bf(fmaxf(o[3], 0.0f)) << 16);
        ov.z = (unsigned)f2bf(fmaxf(o[4], 0.0f)) | ((unsigned)f2bf(fmaxf(o[5], 0.0f)) << 16);
        ov.w = (unsigned)f2bf(fmaxf(o[6], 0.0f)) | ((unsigned)f2bf(fmaxf(o[7], 0.0f)) << 16);
        *(uint4*)(ob + (size_t)n * 64 + c) = ov;
    } else {
        float* of = (float*)outv;
        *(float4*)(of + (size_t)n * 64 + c) = make_float4(o[0], o[1], o[2], o[3]);
        *(float4*)(of + (size_t)n * 64 + c + 4) = make_float4(o[4], o[5], o[6], o[7]);
    }
}

extern "C" void kernel_launch(void* const* d_in, const int* in_sizes, int n_in,
                              void* d_out, int out_size, void* d_ws, size_t ws_size,
                              hipStream_t stream) {
    const float* x      = (const float*)d_in[0];
    const int*   eidx   = (const int*)d_in[1];
    const int*   eattr  = (const int*)d_in[2];
    const float* W1     = (const float*)d_in[3];
    const float* b1     = (const float*)d_in[4];
    const float* ebond1 = (const float*)d_in[5];
    const float* edir1  = (const float*)d_in[6];
    const float* W2     = (const float*)d_in[7];
    const float* b2     = (const float*)d_in[8];
    const float* ebond2 = (const float*)d_in[9];
    const float* edir2  = (const float*)d_in[10];

    const int N = in_sizes[0] / 64;
    const int E = in_sizes[1] / 2;
    const int* src = eidx;
    const int* dst = eidx + E;
    float* out = (float*)d_out;
    const int NB = (N + 1023) >> 10;        // 1024-node coarse bins
    const int SCB = (E + CHUNK - 1) / CHUNK;

    // Workspace (~60 MB of 256 MiB)
    char* w = (char*)d_ws;
    size_t Na = ((size_t)N * 4 + 255) & ~(size_t)255;
    float2* dsc    = (float2*)w;           w += 2 * Na;                       // {dis, scale}
    int*   row_ptr = (int*)w;              w += Na;
    int*   cnt     = (int*)w;              w += Na;
    int*   gcur    = (int*)w;              w += 2 * MAXNB * 4;                // 1 KB cursors
    unsigned int* payD   = (unsigned int*)w;   w += (size_t)MAXNB * BCAP * 4;   // 6.3 MB
    unsigned int* sorted = (unsigned int*)w;   w += (size_t)MAXNB * BCAP * 4;   // 6.3 MB
    unsigned short* payS = (unsigned short*)w; w += (size_t)MAXNB * BCAP * 2;   // 3.1 MB
    unsigned short* Hb   = (unsigned short*)w; w += (size_t)N * 64 * 2;         // 12.8 MB
    unsigned char*  Hq   = (unsigned char*)w;  w += ((size_t)N * 64 + 255) & ~(size_t)255;
    unsigned short* Ab   = (unsigned short*)w; w += (size_t)N * 64 * 2;         // 12.8 MB
    int* gcurS = gcur;
    int* gcurD = gcur + MAXNB;

    const int gT   = (N + 63) / 64;   // gemm tiles
    const int gN16 = (N + 15) / 16;   // aggregate: 16 nodes/block (16 lanes/node)

    // gemm1 tiles ride in K0+K1 (gemm1 depends only on x; done before aggregate 1)
    const int t0 = min(gT, 512);
    const int t1 = gT - t0;

    zero_gemm_kernel<<<1 + t0, THREADS, 0, stream>>>(gcur, 2 * MAXNB, x, W1, b1, Hb, Hq,
                                                     dsc, N, 0);
    scatter_kernel<<<SCB + t1, THREADS, 0, stream>>>(src, dst, eattr, gcurS, gcurD, payS,
                                                     payD, E, NB, SCB, x, W1, b1, Hb, Hq,
                                                     dsc, N, t0);
    build_kernel<<<2 * NB, THREADS, 0, stream>>>(payS, payD, gcurS, gcurD, sorted,
                                                 row_ptr, cnt, NB, dsc, N);

    // layer 1 aggregate: Hb/Hq -> Ab = bf16(relu(aggregate))
    aggregate_kernel<true><<<gN16, THREADS, 0, stream>>>(Hb, Hq, dsc, ebond1, edir1, row_ptr,
                                                         cnt, sorted, Ab, N);

    // layer 2: Ab (bf16) -> Hb/Hq -> d_out (fp32)
    gemm64_kernel<true><<<gT, THREADS, 0, stream>>>(Ab, W2, b2, Hb, Hq, dsc, N);
    aggregate_kernel<false><<<gN16, THREADS, 0, stream>>>(Hb, Hq, dsc, ebond2, edir2, row_ptr,
                                                          cnt, sorted, out, N);
}

// Round 8
// 220.736 us; speedup vs baseline: 1.0630x; 1.0630x over previous
//
#include <hip/hip_runtime.h>

// GCN 2-layer forward (Hu et al. mol-GNN variant) — LDS-sorted coalesced scatter at
// 256-node granularity (512 bins), non-redundant build, bf16+int8 links, MFMA GEMM.
//
//   dis[n] = 1/sqrt(1 + outdeg(n))
//   per layer: h = X@W.T + b; store bf16 rows (self term + next GEMM input) AND
//              per-row-scaled int8 rows (64 B — edge-gather path).
//   out[n] = dis[n]^2*(h_bf16[n]+emb_self) + sum_{e: dst=n} dis[s]*dis[n]*(h_q8[s]*sc[s]+emb_e)
//
// Measured facts / ledger:
//  - R2: VALU GEMM 59us -> MFMA (16x16x32 bf16): gemm off top-5.
//  - R3: isolated 1-4B scatter stores 45us -> LDS counting sort + coalesced runs.
//  - R4..R7 config ledger: R5 (this exact structure) = 221.6us is the measured best;
//    R6 coarse-bin/all-LDS-build = 224.8; R7 16-lane-split aggregate = 234.6 (split
//    solved a non-problem: deg~10 halves leave the 4-wide ILP loop empty, 2x emb-LDS
//    fills, extra shfl combine). This round: R5 restored, ONE change — row_ptr/cnt
//    packed into int2 rc[] (one 8B load per node instead of two dependent 4B loads).
// Payload: src(17b) | emb(5b)<<17 | dstLow8(8b)<<22 (30 bits).

#define THREADS 256
#define NBINS 512    // 256-node buckets, N <= 131072
#define BCAP 4096    // per-bucket edge capacity (mean 2560 @ E=1M,N=100k; sd~51)
#define CHUNK 2048   // edges per scatter block
#define GEMM_SMEM_BYTES (64 * 68 * 4)
// Wv[2048]u32 + SD[2048]u32 + DB[2048]u16 + SDB[2048]u16 + 6*512 ints + 256 ints
#define SC_SMEM (CHUNK * 4 * 2 + CHUNK * 2 * 2 + 6 * NBINS * 4 + 256 * 4)  // 37888

typedef __attribute__((ext_vector_type(8))) short bf16x8;
typedef __attribute__((ext_vector_type(4))) float f32x4;

__device__ __forceinline__ float bflo(unsigned int v) { return __uint_as_float(v << 16); }
__device__ __forceinline__ float bfhi(unsigned int v) { return __uint_as_float(v & 0xFFFF0000u); }
__device__ __forceinline__ unsigned short f2bf(float f) {  // round-to-nearest-even
    unsigned int u = __float_as_uint(f);
    return (unsigned short)((u + 0x7FFFu + ((u >> 16) & 1u)) >> 16);
}
__device__ __forceinline__ int sb(unsigned int w, int j) {  // signed byte j of word
    return (int)(w << (24 - 8 * j)) >> 24;
}

// ---- GEMM tile body (MFMA): Hb = bf16(X @ W.T + B), Hq = int8 per-row-quant.
// 4 waves; wave w owns rows [16w,16w+16) of the 64-row tile, all 64 cols.
// A: lane l&15 = row, 8 contiguous k at 8*(l>>4) (+32 for kstep 1).
// B: lane l&15 = col (W row 16n+(l&15)), same k packing -> k-mapping cancels.
// C/D (m89-verified): col = lane&15, row(within 16-tile) = 4*(lane>>4)+reg.
template <bool XBF16>
__device__ __forceinline__ void gemm64_body(int tile, const void* __restrict__ Xv,
                                            const float* __restrict__ W,
                                            const float* __restrict__ B,
                                            unsigned short* __restrict__ Hb,
                                            unsigned char* __restrict__ Hq,
                                            float2* __restrict__ dsc, int N,
                                            float (*smem)[68]) {
    int t = threadIdx.x;
    int lane = t & 63;
    int wave = __builtin_amdgcn_readfirstlane(t >> 6);
    int l15 = lane & 15;
    int lk = lane >> 4;  // k-chunk id 0..3
    int arow = tile * 64 + wave * 16 + l15;

    bf16x8 a0, a1;
    if (arow < N) {
        if (XBF16) {
            const unsigned short* xp = (const unsigned short*)Xv + (size_t)arow * 64 + 8 * lk;
            a0 = *(const bf16x8*)xp;
            a1 = *(const bf16x8*)(xp + 32);
        } else {
            const float* xp = (const float*)Xv + (size_t)arow * 64 + 8 * lk;
            float4 v0 = *(const float4*)xp;
            float4 v1 = *(const float4*)(xp + 4);
            float4 v2 = *(const float4*)(xp + 32);
            float4 v3 = *(const float4*)(xp + 36);
            a0[0] = (short)f2bf(v0.x); a0[1] = (short)f2bf(v0.y);
            a0[2] = (short)f2bf(v0.z); a0[3] = (short)f2bf(v0.w);
            a0[4] = (short)f2bf(v1.x); a0[5] = (short)f2bf(v1.y);
            a0[6] = (short)f2bf(v1.z); a0[7] = (short)f2bf(v1.w);
            a1[0] = (short)f2bf(v2.x); a1[1] = (short)f2bf(v2.y);
            a1[2] = (short)f2bf(v2.z); a1[3] = (short)f2bf(v2.w);
            a1[4] = (short)f2bf(v3.x); a1[5] = (short)f2bf(v3.y);
            a1[6] = (short)f2bf(v3.z); a1[7] = (short)f2bf(v3.w);
        }
    } else {
#pragma unroll
        for (int e = 0; e < 8; ++e) { a0[e] = 0; a1[e] = 0; }
    }

    bf16x8 bfr[4][2];
#pragma unroll
    for (int n = 0; n < 4; ++n) {
        const float* wp = W + (size_t)(16 * n + l15) * 64 + 8 * lk;
#pragma unroll
        for (int ks = 0; ks < 2; ++ks) {
            float4 u0 = *(const float4*)(wp + 32 * ks);
            float4 u1 = *(const float4*)(wp + 32 * ks + 4);
            bf16x8 bb;
            bb[0] = (short)f2bf(u0.x); bb[1] = (short)f2bf(u0.y);
            bb[2] = (short)f2bf(u0.z); bb[3] = (short)f2bf(u0.w);
            bb[4] = (short)f2bf(u1.x); bb[5] = (short)f2bf(u1.y);
            bb[6] = (short)f2bf(u1.z); bb[7] = (short)f2bf(u1.w);
            bfr[n][ks] = bb;
        }
    }

    f32x4 acc[4];
#pragma unroll
    for (int n = 0; n < 4; ++n) {
        f32x4 z = {0.0f, 0.0f, 0.0f, 0.0f};
        z = __builtin_amdgcn_mfma_f32_16x16x32_bf16(a0, bfr[n][0], z, 0, 0, 0);
        acc[n] = __builtin_amdgcn_mfma_f32_16x16x32_bf16(a1, bfr[n][1], z, 0, 0, 0);
    }

    // bias + stage to LDS: out row (tile-local) = 16*wave + 4*lk + reg, col = 16n+l15.
#pragma unroll
    for (int n = 0; n < 4; ++n) {
        float bv = B[16 * n + l15];
        int col = 16 * n + l15;
#pragma unroll
        for (int r = 0; r < 4; ++r)
            smem[16 * wave + 4 * lk + r][col] = acc[n][r] + bv;
    }
    __syncthreads();

    // writeout: 512 row-groups of 8 floats; 8 contiguous lanes own one row.
#pragma unroll
    for (int i = 0; i < 2; ++i) {
        int idx = t + i * THREADS;
        int r = idx >> 3;
        int c8 = (idx & 7) << 3;
        int grow = tile * 64 + r;
        float4 va = *(const float4*)(&smem[r][c8]);
        float4 vb = *(const float4*)(&smem[r][c8 + 4]);
        float v[8] = {va.x, va.y, va.z, va.w, vb.x, vb.y, vb.z, vb.w};
        float m = fabsf(v[0]);
#pragma unroll
        for (int j = 1; j < 8; ++j) m = fmaxf(m, fabsf(v[j]));
        m = fmaxf(m, __shfl_xor(m, 1));  // 8 lanes/row are contiguous
        m = fmaxf(m, __shfl_xor(m, 2));
        m = fmaxf(m, __shfl_xor(m, 4));
        if (grow < N) {
            uint4 o;
            o.x = (unsigned)f2bf(v[0]) | ((unsigned)f2bf(v[1]) << 16);
            o.y = (unsigned)f2bf(v[2]) | ((unsigned)f2bf(v[3]) << 16);
            o.z = (unsigned)f2bf(v[4]) | ((unsigned)f2bf(v[5]) << 16);
            o.w = (unsigned)f2bf(v[6]) | ((unsigned)f2bf(v[7]) << 16);
            *(uint4*)(Hb + (size_t)grow * 64 + c8) = o;
            float inv = m > 0.0f ? 127.0f / m : 0.0f;
            int q[8];
#pragma unroll
            for (int j = 0; j < 8; ++j) q[j] = __float2int_rn(v[j] * inv);
            uint2 qp;
            qp.x = (unsigned)(q[0] & 255) | ((unsigned)(q[1] & 255) << 8) |
                   ((unsigned)(q[2] & 255) << 16) | ((unsigned)(q[3] & 255) << 24);
            qp.y = (unsigned)(q[4] & 255) | ((unsigned)(q[5] & 255) << 8) |
                   ((unsigned)(q[6] & 255) << 16) | ((unsigned)(q[7] & 255) << 24);
            *(uint2*)(Hq + (size_t)grow * 64 + c8) = qp;
            if ((idx & 7) == 0) dsc[grow].y = m * (1.0f / 127.0f);
        }
    }
}

// ---- K0: zero the bucket cursors (block 0) + gemm1 tiles (blocks 1..) ----
__global__ __launch_bounds__(THREADS) void zero_gemm_kernel(
    int* __restrict__ gcur, int ncur, const float* __restrict__ X,
    const float* __restrict__ W1, const float* __restrict__ B1,
    unsigned short* __restrict__ Hb, unsigned char* __restrict__ Hq,
    float2* __restrict__ dsc, int N, int tile0) {
    __shared__ __align__(16) char sh[GEMM_SMEM_BYTES];
    int b = blockIdx.x;
    if (b == 0) {
        for (int i = threadIdx.x; i < ncur; i += THREADS) gcur[i] = 0;
        return;
    }
    gemm64_body<false>(tile0 + b - 1, X, W1, B1, Hb, Hq, dsc, N, (float(*)[68])sh);
}

// ---- K1: LDS-sorted scatter into 512 bins (256-node buckets). Per block: stage CHUNK
// edges in LDS + bin histograms; one global-atomic reservation per touched bin; in-LDS
// counting sort by dst-bin (payD) and src-bin (payS); linear coalesced writeout.
__global__ __launch_bounds__(THREADS) void scatter_kernel(
    const int* __restrict__ src, const int* __restrict__ dst, const int* __restrict__ attr,
    int* __restrict__ gcurS, int* __restrict__ gcurD, unsigned char* __restrict__ payS,
    unsigned int* __restrict__ payD, int E, int SCB,
    const float* __restrict__ X, const float* __restrict__ W1, const float* __restrict__ B1,
    unsigned short* __restrict__ Hb, unsigned char* __restrict__ Hq,
    float2* __restrict__ dsc, int N, int tile0) {
    __shared__ __align__(16) char sh[SC_SMEM];
    int b = blockIdx.x;
    if (b >= SCB) {
        gemm64_body<false>(tile0 + b - SCB, X, W1, B1, Hb, Hq, dsc, N, (float(*)[68])sh);
        return;
    }
    unsigned int* Wv = (unsigned int*)sh;                 // [CHUNK]
    unsigned int* SD = Wv + CHUNK;                        // [CHUNK] dst-sorted words
    unsigned short* DB = (unsigned short*)(SD + CHUNK);   // [CHUNK] dst bin
    unsigned short* SDB = DB + CHUNK;                     // [CHUNK] sorted dst bin
    int* hD = (int*)(SDB + CHUNK);
    int* hS = hD + NBINS;
    int* mapD = hS + NBINS;
    int* mapS = mapD + NBINS;
    int* curD = mapS + NBINS;
    int* curS = curD + NBINS;
    int* scn = curS + NBINS;                              // [256]
    unsigned char* SS = (unsigned char*)Wv;               // reuse after place-D
    unsigned short* SSB = DB;                             // reuse after place-D

    int t = threadIdx.x;
    for (int k = t; k < NBINS; k += THREADS) { hD[k] = 0; hS[k] = 0; }
    __syncthreads();

    int lo = b * CHUNK, hi = min(E, lo + CHUNK);
    int nch = hi - lo;
    const int2* ap = (const int2*)attr;
    for (int li = t; li < nch; li += THREADS) {
        int i = lo + li;
        int sv = src[i], dv = dst[i];
        int2 a = ap[i];
        Wv[li] = (unsigned int)sv | ((unsigned int)(a.x * 3 + a.y) << 17) |
                 ((unsigned int)(dv & 255) << 22);
        DB[li] = (unsigned short)(dv >> 8);
        atomicAdd(&hD[dv >> 8], 1);  // LDS atomic
        atomicAdd(&hS[sv >> 8], 1);  // LDS atomic
    }
    __syncthreads();

    // reserve global ranges (one atomic per touched bin per stream)
    for (int k = t; k < NBINS; k += THREADS) {
        int h = hD[k];
        int r = h ? atomicAdd(&gcurD[k], h) : 0;  // global atomic, low contention
        mapD[k] = k * BCAP + r;
        int h2 = hS[k];
        int r2 = h2 ? atomicAdd(&gcurS[k], h2) : 0;
        mapS[k] = k * BCAP + r2;
    }
    __syncthreads();

    // exclusive scan of hD over 512 bins (2 bins/thread) -> curD (local start), map adj
    scn[t] = hD[2 * t] + hD[2 * t + 1];
    __syncthreads();
    for (int d = 1; d < THREADS; d <<= 1) {
        int a = (t >= d) ? scn[t - d] : 0;
        __syncthreads();
        scn[t] += a;
        __syncthreads();
    }
    {
        int off = t ? scn[t - 1] : 0;
        curD[2 * t] = off;
        curD[2 * t + 1] = off + hD[2 * t];
        mapD[2 * t] -= off;
        mapD[2 * t + 1] -= off + hD[2 * t];
    }
    __syncthreads();
    // same for hS
    scn[t] = hS[2 * t] + hS[2 * t + 1];
    __syncthreads();
    for (int d = 1; d < THREADS; d <<= 1) {
        int a = (t >= d) ? scn[t - d] : 0;
        __syncthreads();
        scn[t] += a;
        __syncthreads();
    }
    {
        int off = t ? scn[t - 1] : 0;
        curS[2 * t] = off;
        curS[2 * t + 1] = off + hS[2 * t];
        mapS[2 * t] -= off;
        mapS[2 * t + 1] -= off + hS[2 * t];
    }
    __syncthreads();

    // place by dst-bin (consumes Wv/DB into SD/SDB)
    for (int li = t; li < nch; li += THREADS) {
        int k = DB[li];
        int p = atomicAdd(&curD[k], 1);  // LDS atomic
        SD[p] = Wv[li];
        SDB[p] = (unsigned short)k;
    }
    __syncthreads();

    // place by src-bin (sources from SD; reuses Wv region as SS, DB as SSB)
    for (int li = t; li < nch; li += THREADS) {
        int val = (int)(SD[li] & 0x1FFFFu);
        int k = val >> 8;
        int p = atomicAdd(&curS[k], 1);  // LDS atomic
        SS[p] = (unsigned char)(val & 255);
        SSB[p] = (unsigned short)k;
    }
    __syncthreads();

    // linear coalesced writeout
    for (int li = t; li < nch; li += THREADS) {
        payD[mapD[SDB[li]] + li] = SD[li];
        payS[mapS[SSB[li]] + li] = SS[li];
    }
}

// ---- K2: non-redundant build at 256-node buckets. Blocks [0,NB2): out-degree
// histogram of own payS sub-bucket -> dsc.x. Blocks [NB2,2*NB2): 256-bin counting
// sort of own payD sub-bucket -> sorted + rc{row_ptr,cnt}. Independent halves.
__global__ __launch_bounds__(THREADS) void build_kernel(
    const unsigned char* __restrict__ payS, const unsigned int* __restrict__ payD,
    const int* __restrict__ gcurS, const int* __restrict__ gcurD,
    unsigned int* __restrict__ sorted, int2* __restrict__ rc,
    int NB2, float2* __restrict__ dsc, int N) {
    __shared__ int cnt[256];
    __shared__ int cur[256];
    __shared__ int s[THREADS];
    int t = threadIdx.x;
    int b = blockIdx.x;
    if (b < NB2) {
        // phase A: out-degree for bucket b
        int k = b;
        cnt[t] = 0;
        __syncthreads();
        int n = gcurS[k], off = k * BCAP;
        for (int i = t; i < n; i += THREADS) atomicAdd(&cnt[payS[off + i]], 1);  // LDS atomic
        __syncthreads();
        int node = k * 256 + t;
        if (node < N) dsc[node].x = 1.0f / sqrtf(1.0f + (float)cnt[t]);
    } else {
        // phase B: dst counting sort for bucket b-NB2
        int k = b - NB2;
        cnt[t] = 0;
        __syncthreads();
        int ecnt = gcurD[k], eoff = k * BCAP;
        for (int i = t; i < ecnt; i += THREADS)
            atomicAdd(&cnt[(payD[eoff + i] >> 22) & 255], 1);  // LDS atomic
        __syncthreads();
        int v = cnt[t];
        s[t] = v;
        __syncthreads();
        for (int d = 1; d < THREADS; d <<= 1) {
            int a = (t >= d) ? s[t - d] : 0;
            __syncthreads();
            s[t] += a;
            __syncthreads();
        }
        int excl = s[t] - v;
        int node = k * 256 + t;
        if (node < N) rc[node] = make_int2(eoff + excl, v);
        cur[t] = excl;
        __syncthreads();
        for (int i = t; i < ecnt; i += THREADS) {
            unsigned int u = payD[eoff + i];
            int p = atomicAdd(&cur[(u >> 22) & 255], 1);  // LDS atomic
            sorted[eoff + p] = u & 0x3FFFFFu;             // keep src | emb<<17
        }
    }
}

// ---- standalone GEMM wrapper (layer 2) ----
template <bool XBF16>
__global__ __launch_bounds__(THREADS) void gemm64_kernel(const void* __restrict__ Xv,
                                                         const float* __restrict__ W,
                                                         const float* __restrict__ B,
                                                         unsigned short* __restrict__ Hb,
                                                         unsigned char* __restrict__ Hq,
                                                         float2* __restrict__ dsc, int N) {
    __shared__ __align__(16) char sh[GEMM_SMEM_BYTES];
    gemm64_body<XBF16>(blockIdx.x, Xv, W, B, Hb, Hq, dsc, N, (float(*)[68])sh);
}

// ---- aggregate: 8 threads/node (8 dims each), 32 nodes/block, 4-wide edge loop with
// dual accumulators -> up to 32 independent 64B gathers in flight per wave.
__device__ __forceinline__ void edge_acc(unsigned int u, float dn,
                                         const float2* __restrict__ dsc,
                                         const unsigned char* __restrict__ Hq, int c,
                                         const float (*embc)[64], float acc[8]) {
    int s0 = u & 0x1FFFF;
    int e0 = (u >> 17) & 31;
    float2 ds = dsc[s0];
    uint2 q = *(const uint2*)(Hq + (size_t)s0 * 64 + c);
    float w = ds.x * dn, ws = w * ds.y;
    float4 ea = *(const float4*)(&embc[e0][c]);
    float4 eb = *(const float4*)(&embc[e0][c + 4]);
    acc[0] = fmaf(ws, (float)sb(q.x, 0), fmaf(w, ea.x, acc[0]));
    acc[1] = fmaf(ws, (float)sb(q.x, 1), fmaf(w, ea.y, acc[1]));
    acc[2] = fmaf(ws, (float)sb(q.x, 2), fmaf(w, ea.z, acc[2]));
    acc[3] = fmaf(ws, (float)sb(q.x, 3), fmaf(w, ea.w, acc[3]));
    acc[4] = fmaf(ws, (float)sb(q.y, 0), fmaf(w, eb.x, acc[4]));
    acc[5] = fmaf(ws, (float)sb(q.y, 1), fmaf(w, eb.y, acc[5]));
    acc[6] = fmaf(ws, (float)sb(q.y, 2), fmaf(w, eb.z, acc[6]));
    acc[7] = fmaf(ws, (float)sb(q.y, 3), fmaf(w, eb.w, acc[7]));
}

template <bool RELU_BF16_OUT>
__global__ __launch_bounds__(THREADS) void aggregate_kernel(
    const unsigned short* __restrict__ Hb, const unsigned char* __restrict__ Hq,
    const float2* __restrict__ dsc, const float* __restrict__ ebond,
    const float* __restrict__ edir, const int2* __restrict__ rc,
    const unsigned int* __restrict__ entries, void* __restrict__ outv, int N) {
    __shared__ float embc[18][64];
    int t = threadIdx.x;
    for (int i = t; i < 18 * 64; i += THREADS) {
        int row = i >> 6, c = i & 63;
        embc[row][c] = ebond[(row / 3) * 64 + c] + edir[(row % 3) * 64 + c];
    }
    __syncthreads();

    int n = blockIdx.x * 32 + (t >> 3);
    if (n >= N) return;
    int c = (t & 7) << 3;

    float dn = dsc[n].x;
    uint4 hv = *(const uint4*)(Hb + (size_t)n * 64 + c);
    float4 ea = *(const float4*)(&embc[12][c]);  // self-loop: bt=4, bd=0 -> idx 12
    float4 eb = *(const float4*)(&embc[12][c + 4]);
    float nrm = dn * dn;
    float accA[8], accB[8];
    accA[0] = nrm * (bflo(hv.x) + ea.x);
    accA[1] = nrm * (bfhi(hv.x) + ea.y);
    accA[2] = nrm * (bflo(hv.y) + ea.z);
    accA[3] = nrm * (bfhi(hv.y) + ea.w);
    accA[4] = nrm * (bflo(hv.z) + eb.x);
    accA[5] = nrm * (bfhi(hv.z) + eb.y);
    accA[6] = nrm * (bflo(hv.w) + eb.z);
    accA[7] = nrm * (bfhi(hv.w) + eb.w);
#pragma unroll
    for (int j = 0; j < 8; ++j) accB[j] = 0.0f;

    int2 pc = rc[n];
    int p = pc.x;
    int end = p + pc.y;
    const float(*ec)[64] = (const float(*)[64])embc;
    for (; p + 3 < end; p += 4) {
        unsigned int u0 = entries[p];
        unsigned int u1 = entries[p + 1];
        unsigned int u2 = entries[p + 2];
        unsigned int u3 = entries[p + 3];
        edge_acc(u0, dn, dsc, Hq, c, ec, accA);
        edge_acc(u1, dn, dsc, Hq, c, ec, accB);
        edge_acc(u2, dn, dsc, Hq, c, ec, accA);
        edge_acc(u3, dn, dsc, Hq, c, ec, accB);
    }
    for (; p < end; ++p) edge_acc(entries[p], dn, dsc, Hq, c, ec, accA);

    float o[8];
#pragma unroll
    for (int j = 0; j < 8; ++j) o[j] = accA[j] + accB[j];

    if (RELU_BF16_OUT) {
        unsigned short* ob = (unsigned short*)outv;
        uint4 ov;
        ov.x = (unsigned)f2bf(fmaxf(o[0], 0.0f)) | ((unsigned)f2bf(fmaxf(o[1], 0.0f)) << 16);
        ov.y = (unsigned)f2bf(fmaxf(o[2], 0.0f)) | ((unsigned)f2bf(fmaxf(o[3], 0.0f)) << 16);
        ov.z = (unsigned)f2bf(fmaxf(o[4], 0.0f)) | ((unsigned)f2bf(fmaxf(o[5], 0.0f)) << 16);
        ov.w = (unsigned)f2bf(fmaxf(o[6], 0.0f)) | ((unsigned)f2bf(fmaxf(o[7], 0.0f)) << 16);
        *(uint4*)(ob + (size_t)n * 64 + c) = ov;
    } else {
        float* of = (float*)outv;
        *(float4*)(of + (size_t)n * 64 + c) = make_float4(o[0], o[1], o[2], o[3]);
        *(float4*)(of + (size_t)n * 64 + c + 4) = make_float4(o[4], o[5], o[6], o[7]);
    }
}

extern "C" void kernel_launch(void* const* d_in, const int* in_sizes, int n_in,
                              void* d_out, int out_size, void* d_ws, size_t ws_size,
                              hipStream_t stream) {
    const float* x      = (const float*)d_in[0];
    const int*   eidx   = (const int*)d_in[1];
    const int*   eattr  = (const int*)d_in[2];
    const float* W1     = (const float*)d_in[3];
    const float* b1     = (const float*)d_in[4];
    const float* ebond1 = (const float*)d_in[5];
    const float* edir1  = (const float*)d_in[6];
    const float* W2     = (const float*)d_in[7];
    const float* b2     = (const float*)d_in[8];
    const float* ebond2 = (const float*)d_in[9];
    const float* edir2  = (const float*)d_in[10];

    const int N = in_sizes[0] / 64;
    const int E = in_sizes[1] / 2;
    const int* src = eidx;
    const int* dst = eidx + E;
    float* out = (float*)d_out;
    const int NB2 = (N + 255) >> 8;         // 256-node buckets
    const int SCB = (E + CHUNK - 1) / CHUNK;

    // Workspace (~52 MB of 256 MiB)
    char* w = (char*)d_ws;
    size_t Na = ((size_t)N * 4 + 255) & ~(size_t)255;
    float2* dsc    = (float2*)w;           w += 2 * Na;                       // {dis, scale}
    int2*  rc      = (int2*)w;             w += 2 * Na;                       // {row_ptr,cnt}
    int*   gcur    = (int*)w;              w += 2 * NBINS * 4;                // 4 KB cursors
    unsigned int* payD   = (unsigned int*)w;   w += (size_t)NBINS * BCAP * 4;   // 8 MB
    unsigned int* sorted = (unsigned int*)w;   w += (size_t)NBINS * BCAP * 4;   // 8 MB
    unsigned char* payS  = (unsigned char*)w;  w += (size_t)NBINS * BCAP;       // 2 MB
    unsigned short* Hb   = (unsigned short*)w; w += (size_t)N * 64 * 2;         // 12.8 MB
    unsigned char*  Hq   = (unsigned char*)w;  w += ((size_t)N * 64 + 255) & ~(size_t)255;
    unsigned short* Ab   = (unsigned short*)w; w += (size_t)N * 64 * 2;         // 12.8 MB
    int* gcurS = gcur;
    int* gcurD = gcur + NBINS;

    const int gT   = (N + 63) / 64;   // gemm tiles
    const int gN32 = (N + 31) / 32;   // aggregate: 32 nodes/block

    // all gemm1 tiles ride in K0+K1 (gemm1 depends only on x; must be done before agg1)
    const int t0 = min(gT, 512);
    const int t1 = gT - t0;

    zero_gemm_kernel<<<1 + t0, THREADS, 0, stream>>>(gcur, 2 * NBINS, x, W1, b1, Hb, Hq,
                                                     dsc, N, 0);
    scatter_kernel<<<SCB + t1, THREADS, 0, stream>>>(src, dst, eattr, gcurS, gcurD, payS,
                                                     payD, E, SCB, x, W1, b1, Hb, Hq,
                                                     dsc, N, t0);
    build_kernel<<<2 * NB2, THREADS, 0, stream>>>(payS, payD, gcurS, gcurD, sorted,
                                                  rc, NB2, dsc, N);

    // layer 1 aggregate: Hb/Hq -> Ab = bf16(relu(aggregate))
    aggregate_kernel<true><<<gN32, THREADS, 0, stream>>>(Hb, Hq, dsc, ebond1, edir1, rc,
                                                         sorted, Ab, N);

    // layer 2: Ab (bf16) -> Hb/Hq -> d_out (fp32)
    gemm64_kernel<true><<<gT, THREADS, 0, stream>>>(Ab, W2, b2, Hb, Hq, dsc, N);
    aggregate_kernel<false><<<gN32, THREADS, 0, stream>>>(Hb, Hq, dsc, ebond2, edir2, rc,
                                                          sorted, out, N);
}

// Round 10
// 220.304 us; speedup vs baseline: 1.0651x; 1.0020x over previous
//
#include <hip/hip_runtime.h>

// GCN 2-layer forward (Hu et al. mol-GNN variant) — LDS-sorted coalesced scatter at
// 256-node granularity (512 bins), non-redundant build, bf16+int8 links, MFMA GEMM,
// FUSED aggregate1+gemm2 (Ab buffer eliminated).
//
//   dis[n] = 1/sqrt(1 + outdeg(n))
//   per layer: h = X@W.T + b; store bf16 rows (self term) AND per-row-scaled int8
//              rows (64 B — edge-gather path).
//   out[n] = dis[n]^2*(h_bf16[n]+emb_self) + sum_{e: dst=n} dis[s]*dis[n]*(h_q8[s]*sc[s]+emb_e)
//
// Measured facts / ledger:
//  - R2: VALU GEMM 59us -> MFMA: gemm off top-5. R3: LDS-sorted coalesced scatter.
//  - R4..R8: granularity/lane-geometry knobs plateau at 220-235us; R8 = 220.7 best
//    (R5 structure + rc int2 packing). All kernels in the 10-40us unsaturated band ->
//    structural launches/traffic are the remaining cost.
//  - R9: fused agg1+gemm2 — bench hit an INFRA failure (container died twice, no
//    result). Kernel audited: 31232B static LDS in fused kernel, no divergent
//    barriers, no ordering races, all writes guarded. Resubmitting IDENTICAL source
//    for clean attribution (R10 = R9 retry).
//  - Fusion rationale: gemm2 row n depends only on agg1 row n -> fuse per 64-node
//    tile. agg1 results go bf16 -> LDS tile -> MFMA A-fragments; Ab (12.8MB w +
//    12.8MB r) and one launch boundary are deleted. Layer buffers split (Hb1/Hq1/dsc
//    vs Hb2/Hq2/dsc2) to avoid read/write races inside the fused kernel. Numerics
//    bit-identical to R8 -> absmax must stay 0.0078125.
// Payload: src(17b) | emb(5b)<<17 | dstLow8(8b)<<22 (30 bits).

#define THREADS 256
#define NBINS 512    // 256-node buckets, N <= 131072
#define BCAP 4096    // per-bucket edge capacity (mean 2560 @ E=1M,N=100k; sd~51)
#define CHUNK 2048   // edges per scatter block
#define GEMM_SMEM_BYTES (64 * 68 * 4)
// Wv[2048]u32 + SD[2048]u32 + DB[2048]u16 + SDB[2048]u16 + 6*512 ints + 256 ints
#define SC_SMEM (CHUNK * 4 * 2 + CHUNK * 2 * 2 + 6 * NBINS * 4 + 256 * 4)  // 37888

typedef __attribute__((ext_vector_type(8))) short bf16x8;
typedef __attribute__((ext_vector_type(4))) float f32x4;

__device__ __forceinline__ float bflo(unsigned int v) { return __uint_as_float(v << 16); }
__device__ __forceinline__ float bfhi(unsigned int v) { return __uint_as_float(v & 0xFFFF0000u); }
__device__ __forceinline__ unsigned short f2bf(float f) {  // round-to-nearest-even
    unsigned int u = __float_as_uint(f);
    return (unsigned short)((u + 0x7FFFu + ((u >> 16) & 1u)) >> 16);
}
__device__ __forceinline__ int sb(unsigned int w, int j) {  // signed byte j of word
    return (int)(w << (24 - 8 * j)) >> 24;
}

// ---- shared GEMM core pieces -------------------------------------------------
// B-fragment load: W row 16n+(l15), k-chunk lk; fp32 -> bf16 in-register.
__device__ __forceinline__ void load_bfrags(const float* __restrict__ W, int l15, int lk,
                                            bf16x8 bfr[4][2]) {
#pragma unroll
    for (int n = 0; n < 4; ++n) {
        const float* wp = W + (size_t)(16 * n + l15) * 64 + 8 * lk;
#pragma unroll
        for (int ks = 0; ks < 2; ++ks) {
            float4 u0 = *(const float4*)(wp + 32 * ks);
            float4 u1 = *(const float4*)(wp + 32 * ks + 4);
            bf16x8 bb;
            bb[0] = (short)f2bf(u0.x); bb[1] = (short)f2bf(u0.y);
            bb[2] = (short)f2bf(u0.z); bb[3] = (short)f2bf(u0.w);
            bb[4] = (short)f2bf(u1.x); bb[5] = (short)f2bf(u1.y);
            bb[6] = (short)f2bf(u1.z); bb[7] = (short)f2bf(u1.w);
            bfr[n][ks] = bb;
        }
    }
}

// epilogue: bias+stage smC, then bf16 row + int8 quant row + scale writeout.
// DSC2: if nonnull, write {dissrc.x, scale} there (fused layer-2); else dscy[grow].y.
__device__ __forceinline__ void gemm_epilogue(int tile, f32x4 acc[4],
                                              const float* __restrict__ B, int wave,
                                              int l15, int lk, int t,
                                              unsigned short* __restrict__ Hb,
                                              unsigned char* __restrict__ Hq,
                                              float2* __restrict__ dscy,
                                              const float2* __restrict__ dsrc,
                                              float2* __restrict__ dsc2, int N,
                                              float (*smem)[68]) {
#pragma unroll
    for (int n = 0; n < 4; ++n) {
        float bv = B[16 * n + l15];
        int col = 16 * n + l15;
#pragma unroll
        for (int r = 0; r < 4; ++r)
            smem[16 * wave + 4 * lk + r][col] = acc[n][r] + bv;
    }
    __syncthreads();

#pragma unroll
    for (int i = 0; i < 2; ++i) {
        int idx = t + i * THREADS;
        int r = idx >> 3;
        int c8 = (idx & 7) << 3;
        int grow = tile * 64 + r;
        float4 va = *(const float4*)(&smem[r][c8]);
        float4 vb = *(const float4*)(&smem[r][c8 + 4]);
        float v[8] = {va.x, va.y, va.z, va.w, vb.x, vb.y, vb.z, vb.w};
        float m = fabsf(v[0]);
#pragma unroll
        for (int j = 1; j < 8; ++j) m = fmaxf(m, fabsf(v[j]));
        m = fmaxf(m, __shfl_xor(m, 1));  // 8 lanes/row are contiguous
        m = fmaxf(m, __shfl_xor(m, 2));
        m = fmaxf(m, __shfl_xor(m, 4));
        if (grow < N) {
            uint4 o;
            o.x = (unsigned)f2bf(v[0]) | ((unsigned)f2bf(v[1]) << 16);
            o.y = (unsigned)f2bf(v[2]) | ((unsigned)f2bf(v[3]) << 16);
            o.z = (unsigned)f2bf(v[4]) | ((unsigned)f2bf(v[5]) << 16);
            o.w = (unsigned)f2bf(v[6]) | ((unsigned)f2bf(v[7]) << 16);
            *(uint4*)(Hb + (size_t)grow * 64 + c8) = o;
            float inv = m > 0.0f ? 127.0f / m : 0.0f;
            int q[8];
#pragma unroll
            for (int j = 0; j < 8; ++j) q[j] = __float2int_rn(v[j] * inv);
            uint2 qp;
            qp.x = (unsigned)(q[0] & 255) | ((unsigned)(q[1] & 255) << 8) |
                   ((unsigned)(q[2] & 255) << 16) | ((unsigned)(q[3] & 255) << 24);
            qp.y = (unsigned)(q[4] & 255) | ((unsigned)(q[5] & 255) << 8) |
                   ((unsigned)(q[6] & 255) << 16) | ((unsigned)(q[7] & 255) << 24);
            *(uint2*)(Hq + (size_t)grow * 64 + c8) = qp;
            if ((idx & 7) == 0) {
                float sc = m * (1.0f / 127.0f);
                if (dsc2) dsc2[grow] = make_float2(dsrc[grow].x, sc);
                else dscy[grow].y = sc;
            }
        }
    }
}

// ---- GEMM tile body (MFMA), A from global fp32 (layer 1 riders) ----
__device__ __forceinline__ void gemm64_body(int tile, const float* __restrict__ Xv,
                                            const float* __restrict__ W,
                                            const float* __restrict__ B,
                                            unsigned short* __restrict__ Hb,
                                            unsigned char* __restrict__ Hq,
                                            float2* __restrict__ dsc, int N,
                                            float (*smem)[68]) {
    int t = threadIdx.x;
    int lane = t & 63;
    int wave = __builtin_amdgcn_readfirstlane(t >> 6);
    int l15 = lane & 15;
    int lk = lane >> 4;  // k-chunk id 0..3
    int arow = tile * 64 + wave * 16 + l15;

    bf16x8 a0, a1;
    if (arow < N) {
        const float* xp = Xv + (size_t)arow * 64 + 8 * lk;
        float4 v0 = *(const float4*)xp;
        float4 v1 = *(const float4*)(xp + 4);
        float4 v2 = *(const float4*)(xp + 32);
        float4 v3 = *(const float4*)(xp + 36);
        a0[0] = (short)f2bf(v0.x); a0[1] = (short)f2bf(v0.y);
        a0[2] = (short)f2bf(v0.z); a0[3] = (short)f2bf(v0.w);
        a0[4] = (short)f2bf(v1.x); a0[5] = (short)f2bf(v1.y);
        a0[6] = (short)f2bf(v1.z); a0[7] = (short)f2bf(v1.w);
        a1[0] = (short)f2bf(v2.x); a1[1] = (short)f2bf(v2.y);
        a1[2] = (short)f2bf(v2.z); a1[3] = (short)f2bf(v2.w);
        a1[4] = (short)f2bf(v3.x); a1[5] = (short)f2bf(v3.y);
        a1[6] = (short)f2bf(v3.z); a1[7] = (short)f2bf(v3.w);
    } else {
#pragma unroll
        for (int e = 0; e < 8; ++e) { a0[e] = 0; a1[e] = 0; }
    }

    bf16x8 bfr[4][2];
    load_bfrags(W, l15, lk, bfr);

    f32x4 acc[4];
#pragma unroll
    for (int n = 0; n < 4; ++n) {
        f32x4 z = {0.0f, 0.0f, 0.0f, 0.0f};
        z = __builtin_amdgcn_mfma_f32_16x16x32_bf16(a0, bfr[n][0], z, 0, 0, 0);
        acc[n] = __builtin_amdgcn_mfma_f32_16x16x32_bf16(a1, bfr[n][1], z, 0, 0, 0);
    }
    gemm_epilogue(tile, acc, B, wave, l15, lk, t, Hb, Hq, dsc, nullptr, nullptr, N, smem);
}

// ---- K0: zero the bucket cursors (block 0) + gemm1 tiles (blocks 1..) ----
__global__ __launch_bounds__(THREADS) void zero_gemm_kernel(
    int* __restrict__ gcur, int ncur, const float* __restrict__ X,
    const float* __restrict__ W1, const float* __restrict__ B1,
    unsigned short* __restrict__ Hb, unsigned char* __restrict__ Hq,
    float2* __restrict__ dsc, int N, int tile0) {
    __shared__ __align__(16) char sh[GEMM_SMEM_BYTES];
    int b = blockIdx.x;
    if (b == 0) {
        for (int i = threadIdx.x; i < ncur; i += THREADS) gcur[i] = 0;
        return;
    }
    gemm64_body(tile0 + b - 1, X, W1, B1, Hb, Hq, dsc, N, (float(*)[68])sh);
}

// ---- K1: LDS-sorted scatter into 512 bins (256-node buckets). Per block: stage CHUNK
// edges in LDS + bin histograms; one global-atomic reservation per touched bin; in-LDS
// counting sort by dst-bin (payD) and src-bin (payS); linear coalesced writeout.
__global__ __launch_bounds__(THREADS) void scatter_kernel(
    const int* __restrict__ src, const int* __restrict__ dst, const int* __restrict__ attr,
    int* __restrict__ gcurS, int* __restrict__ gcurD, unsigned char* __restrict__ payS,
    unsigned int* __restrict__ payD, int E, int SCB,
    const float* __restrict__ X, const float* __restrict__ W1, const float* __restrict__ B1,
    unsigned short* __restrict__ Hb, unsigned char* __restrict__ Hq,
    float2* __restrict__ dsc, int N, int tile0) {
    __shared__ __align__(16) char sh[SC_SMEM];
    int b = blockIdx.x;
    if (b >= SCB) {
        gemm64_body(tile0 + b - SCB, X, W1, B1, Hb, Hq, dsc, N, (float(*)[68])sh);
        return;
    }
    unsigned int* Wv = (unsigned int*)sh;                 // [CHUNK]
    unsigned int* SD = Wv + CHUNK;                        // [CHUNK] dst-sorted words
    unsigned short* DB = (unsigned short*)(SD + CHUNK);   // [CHUNK] dst bin
    unsigned short* SDB = DB + CHUNK;                     // [CHUNK] sorted dst bin
    int* hD = (int*)(SDB + CHUNK);
    int* hS = hD + NBINS;
    int* mapD = hS + NBINS;
    int* mapS = mapD + NBINS;
    int* curD = mapS + NBINS;
    int* curS = curD + NBINS;
    int* scn = curS + NBINS;                              // [256]
    unsigned char* SS = (unsigned char*)Wv;               // reuse after place-D
    unsigned short* SSB = DB;                             // reuse after place-D

    int t = threadIdx.x;
    for (int k = t; k < NBINS; k += THREADS) { hD[k] = 0; hS[k] = 0; }
    __syncthreads();

    int lo = b * CHUNK, hi = min(E, lo + CHUNK);
    int nch = hi - lo;
    const int2* ap = (const int2*)attr;
    for (int li = t; li < nch; li += THREADS) {
        int i = lo + li;
        int sv = src[i], dv = dst[i];
        int2 a = ap[i];
        Wv[li] = (unsigned int)sv | ((unsigned int)(a.x * 3 + a.y) << 17) |
                 ((unsigned int)(dv & 255) << 22);
        DB[li] = (unsigned short)(dv >> 8);
        atomicAdd(&hD[dv >> 8], 1);  // LDS atomic
        atomicAdd(&hS[sv >> 8], 1);  // LDS atomic
    }
    __syncthreads();

    // reserve global ranges (one atomic per touched bin per stream)
    for (int k = t; k < NBINS; k += THREADS) {
        int h = hD[k];
        int r = h ? atomicAdd(&gcurD[k], h) : 0;  // global atomic, low contention
        mapD[k] = k * BCAP + r;
        int h2 = hS[k];
        int r2 = h2 ? atomicAdd(&gcurS[k], h2) : 0;
        mapS[k] = k * BCAP + r2;
    }
    __syncthreads();

    // exclusive scan of hD over 512 bins (2 bins/thread) -> curD (local start), map adj
    scn[t] = hD[2 * t] + hD[2 * t + 1];
    __syncthreads();
    for (int d = 1; d < THREADS; d <<= 1) {
        int a = (t >= d) ? scn[t - d] : 0;
        __syncthreads();
        scn[t] += a;
        __syncthreads();
    }
    {
        int off = t ? scn[t - 1] : 0;
        curD[2 * t] = off;
        curD[2 * t + 1] = off + hD[2 * t];
        mapD[2 * t] -= off;
        mapD[2 * t + 1] -= off + hD[2 * t];
    }
    __syncthreads();
    // same for hS
    scn[t] = hS[2 * t] + hS[2 * t + 1];
    __syncthreads();
    for (int d = 1; d < THREADS; d <<= 1) {
        int a = (t >= d) ? scn[t - d] : 0;
        __syncthreads();
        scn[t] += a;
        __syncthreads();
    }
    {
        int off = t ? scn[t - 1] : 0;
        curS[2 * t] = off;
        curS[2 * t + 1] = off + hS[2 * t];
        mapS[2 * t] -= off;
        mapS[2 * t + 1] -= off + hS[2 * t];
    }
    __syncthreads();

    // place by dst-bin (consumes Wv/DB into SD/SDB)
    for (int li = t; li < nch; li += THREADS) {
        int k = DB[li];
        int p = atomicAdd(&curD[k], 1);  // LDS atomic
        SD[p] = Wv[li];
        SDB[p] = (unsigned short)k;
    }
    __syncthreads();

    // place by src-bin (sources from SD; reuses Wv region as SS, DB as SSB)
    for (int li = t; li < nch; li += THREADS) {
        int val = (int)(SD[li] & 0x1FFFFu);
        int k = val >> 8;
        int p = atomicAdd(&curS[k], 1);  // LDS atomic
        SS[p] = (unsigned char)(val & 255);
        SSB[p] = (unsigned short)k;
    }
    __syncthreads();

    // linear coalesced writeout
    for (int li = t; li < nch; li += THREADS) {
        payD[mapD[SDB[li]] + li] = SD[li];
        payS[mapS[SSB[li]] + li] = SS[li];
    }
}

// ---- K2: non-redundant build at 256-node buckets. Blocks [0,NB2): out-degree
// histogram of own payS sub-bucket -> dsc.x. Blocks [NB2,2*NB2): 256-bin counting
// sort of own payD sub-bucket -> sorted + rc{row_ptr,cnt}. Independent halves.
__global__ __launch_bounds__(THREADS) void build_kernel(
    const unsigned char* __restrict__ payS, const unsigned int* __restrict__ payD,
    const int* __restrict__ gcurS, const int* __restrict__ gcurD,
    unsigned int* __restrict__ sorted, int2* __restrict__ rc,
    int NB2, float2* __restrict__ dsc, int N) {
    __shared__ int cnt[256];
    __shared__ int cur[256];
    __shared__ int s[THREADS];
    int t = threadIdx.x;
    int b = blockIdx.x;
    if (b < NB2) {
        // phase A: out-degree for bucket b
        int k = b;
        cnt[t] = 0;
        __syncthreads();
        int n = gcurS[k], off = k * BCAP;
        for (int i = t; i < n; i += THREADS) atomicAdd(&cnt[payS[off + i]], 1);  // LDS atomic
        __syncthreads();
        int node = k * 256 + t;
        if (node < N) dsc[node].x = 1.0f / sqrtf(1.0f + (float)cnt[t]);
    } else {
        // phase B: dst counting sort for bucket b-NB2
        int k = b - NB2;
        cnt[t] = 0;
        __syncthreads();
        int ecnt = gcurD[k], eoff = k * BCAP;
        for (int i = t; i < ecnt; i += THREADS)
            atomicAdd(&cnt[(payD[eoff + i] >> 22) & 255], 1);  // LDS atomic
        __syncthreads();
        int v = cnt[t];
        s[t] = v;
        __syncthreads();
        for (int d = 1; d < THREADS; d <<= 1) {
            int a = (t >= d) ? s[t - d] : 0;
            __syncthreads();
            s[t] += a;
            __syncthreads();
        }
        int excl = s[t] - v;
        int node = k * 256 + t;
        if (node < N) rc[node] = make_int2(eoff + excl, v);
        cur[t] = excl;
        __syncthreads();
        for (int i = t; i < ecnt; i += THREADS) {
            unsigned int u = payD[eoff + i];
            int p = atomicAdd(&cur[(u >> 22) & 255], 1);  // LDS atomic
            sorted[eoff + p] = u & 0x3FFFFFu;             // keep src | emb<<17
        }
    }
}

// ---- aggregate inner step: 8 lanes/node, 8 dims/lane ----
__device__ __forceinline__ void edge_acc(unsigned int u, float dn,
                                         const float2* __restrict__ dsc,
                                         const unsigned char* __restrict__ Hq, int c,
                                         const float (*embc)[64], float acc[8]) {
    int s0 = u & 0x1FFFF;
    int e0 = (u >> 17) & 31;
    float2 ds = dsc[s0];
    uint2 q = *(const uint2*)(Hq + (size_t)s0 * 64 + c);
    float w = ds.x * dn, ws = w * ds.y;
    float4 ea = *(const float4*)(&embc[e0][c]);
    float4 eb = *(const float4*)(&embc[e0][c + 4]);
    acc[0] = fmaf(ws, (float)sb(q.x, 0), fmaf(w, ea.x, acc[0]));
    acc[1] = fmaf(ws, (float)sb(q.x, 1), fmaf(w, ea.y, acc[1]));
    acc[2] = fmaf(ws, (float)sb(q.x, 2), fmaf(w, ea.z, acc[2]));
    acc[3] = fmaf(ws, (float)sb(q.x, 3), fmaf(w, ea.w, acc[3]));
    acc[4] = fmaf(ws, (float)sb(q.y, 0), fmaf(w, eb.x, acc[4]));
    acc[5] = fmaf(ws, (float)sb(q.y, 1), fmaf(w, eb.y, acc[5]));
    acc[6] = fmaf(ws, (float)sb(q.y, 2), fmaf(w, eb.z, acc[6]));
    acc[7] = fmaf(ws, (float)sb(q.y, 3), fmaf(w, eb.w, acc[7]));
}

// full per-node aggregate (4-wide, dual accumulators); returns o[8] for dims [c,c+8)
__device__ __forceinline__ void agg_node(int n, int c, const unsigned short* __restrict__ Hb,
                                         const unsigned char* __restrict__ Hq,
                                         const float2* __restrict__ dsc,
                                         const int2* __restrict__ rc,
                                         const unsigned int* __restrict__ entries,
                                         const float (*ec)[64], float o[8]) {
    float dn = dsc[n].x;
    uint4 hv = *(const uint4*)(Hb + (size_t)n * 64 + c);
    float4 ea = *(const float4*)(&ec[12][c]);  // self-loop: bt=4, bd=0 -> idx 12
    float4 eb = *(const float4*)(&ec[12][c + 4]);
    float nrm = dn * dn;
    float accA[8], accB[8];
    accA[0] = nrm * (bflo(hv.x) + ea.x);
    accA[1] = nrm * (bfhi(hv.x) + ea.y);
    accA[2] = nrm * (bflo(hv.y) + ea.z);
    accA[3] = nrm * (bfhi(hv.y) + ea.w);
    accA[4] = nrm * (bflo(hv.z) + eb.x);
    accA[5] = nrm * (bfhi(hv.z) + eb.y);
    accA[6] = nrm * (bflo(hv.w) + eb.z);
    accA[7] = nrm * (bfhi(hv.w) + eb.w);
#pragma unroll
    for (int j = 0; j < 8; ++j) accB[j] = 0.0f;

    int2 pc = rc[n];
    int p = pc.x;
    int end = p + pc.y;
    for (; p + 3 < end; p += 4) {
        unsigned int u0 = entries[p];
        unsigned int u1 = entries[p + 1];
        unsigned int u2 = entries[p + 2];
        unsigned int u3 = entries[p + 3];
        edge_acc(u0, dn, dsc, Hq, c, ec, accA);
        edge_acc(u1, dn, dsc, Hq, c, ec, accB);
        edge_acc(u2, dn, dsc, Hq, c, ec, accA);
        edge_acc(u3, dn, dsc, Hq, c, ec, accB);
    }
    for (; p < end; ++p) edge_acc(entries[p], dn, dsc, Hq, c, ec, accA);
#pragma unroll
    for (int j = 0; j < 8; ++j) o[j] = accA[j] + accB[j];
}

// ---- K3 FUSED: aggregate layer 1 (ReLU, bf16) for 64 nodes -> LDS tile -> MFMA
// gemm2 -> Hb2/Hq2/dsc2. No Ab round-trip, no extra launch.
__global__ __launch_bounds__(THREADS) void agg_gemm_kernel(
    const unsigned short* __restrict__ Hb1, const unsigned char* __restrict__ Hq1,
    const float2* __restrict__ dsc, const float* __restrict__ ebond,
    const float* __restrict__ edir, const int2* __restrict__ rc,
    const unsigned int* __restrict__ entries, const float* __restrict__ W,
    const float* __restrict__ B, unsigned short* __restrict__ Hb2,
    unsigned char* __restrict__ Hq2, float2* __restrict__ dsc2, int N) {
    __shared__ float embc[18][64];
    __shared__ __align__(16) unsigned short smA[64][72];  // bf16 A-tile, stride 72
    __shared__ __align__(16) float smC[64][68];           // epilogue staging
    int t = threadIdx.x;
    for (int i = t; i < 18 * 64; i += THREADS) {
        int row = i >> 6, c = i & 63;
        embc[row][c] = ebond[(row / 3) * 64 + c] + edir[(row % 3) * 64 + c];
    }
    __syncthreads();

    int tile = blockIdx.x;
    const float(*ec)[64] = (const float(*)[64])embc;
#pragma unroll 1
    for (int r = 0; r < 2; ++r) {
        int ln = r * 32 + (t >> 3);  // local row 0..63
        int n = tile * 64 + ln;
        int c = (t & 7) << 3;
        uint4 ov = make_uint4(0u, 0u, 0u, 0u);
        if (n < N) {
            float o[8];
            agg_node(n, c, Hb1, Hq1, dsc, rc, entries, ec, o);
            ov.x = (unsigned)f2bf(fmaxf(o[0], 0.0f)) | ((unsigned)f2bf(fmaxf(o[1], 0.0f)) << 16);
            ov.y = (unsigned)f2bf(fmaxf(o[2], 0.0f)) | ((unsigned)f2bf(fmaxf(o[3], 0.0f)) << 16);
            ov.z = (unsigned)f2bf(fmaxf(o[4], 0.0f)) | ((unsigned)f2bf(fmaxf(o[5], 0.0f)) << 16);
            ov.w = (unsigned)f2bf(fmaxf(o[6], 0.0f)) | ((unsigned)f2bf(fmaxf(o[7], 0.0f)) << 16);
        }
        *(uint4*)(&smA[ln][c]) = ov;  // (ln*72 + c)*2 bytes: 16B-aligned
    }
    __syncthreads();

    // gemm2 from the LDS A-tile
    int lane = t & 63;
    int wave = __builtin_amdgcn_readfirstlane(t >> 6);
    int l15 = lane & 15;
    int lk = lane >> 4;
    int lrow = wave * 16 + l15;
    bf16x8 a0 = *(const bf16x8*)(&smA[lrow][8 * lk]);
    bf16x8 a1 = *(const bf16x8*)(&smA[lrow][8 * lk + 32]);

    bf16x8 bfr[4][2];
    load_bfrags(W, l15, lk, bfr);

    f32x4 acc[4];
#pragma unroll
    for (int n = 0; n < 4; ++n) {
        f32x4 z = {0.0f, 0.0f, 0.0f, 0.0f};
        z = __builtin_amdgcn_mfma_f32_16x16x32_bf16(a0, bfr[n][0], z, 0, 0, 0);
        acc[n] = __builtin_amdgcn_mfma_f32_16x16x32_bf16(a1, bfr[n][1], z, 0, 0, 0);
    }
    gemm_epilogue(tile, acc, B, wave, l15, lk, t, Hb2, Hq2, nullptr, dsc, dsc2, N, smC);
}

// ---- K4: standalone aggregate (layer 2 -> fp32 out) ----
__global__ __launch_bounds__(THREADS) void aggregate_kernel(
    const unsigned short* __restrict__ Hb, const unsigned char* __restrict__ Hq,
    const float2* __restrict__ dsc, const float* __restrict__ ebond,
    const float* __restrict__ edir, const int2* __restrict__ rc,
    const unsigned int* __restrict__ entries, float* __restrict__ out, int N) {
    __shared__ float embc[18][64];
    int t = threadIdx.x;
    for (int i = t; i < 18 * 64; i += THREADS) {
        int row = i >> 6, c = i & 63;
        embc[row][c] = ebond[(row / 3) * 64 + c] + edir[(row % 3) * 64 + c];
    }
    __syncthreads();

    int n = blockIdx.x * 32 + (t >> 3);
    if (n >= N) return;
    int c = (t & 7) << 3;
    float o[8];
    agg_node(n, c, Hb, Hq, dsc, rc, entries, (const float(*)[64])embc, o);
    *(float4*)(out + (size_t)n * 64 + c) = make_float4(o[0], o[1], o[2], o[3]);
    *(float4*)(out + (size_t)n * 64 + c + 4) = make_float4(o[4], o[5], o[6], o[7]);
}

extern "C" void kernel_launch(void* const* d_in, const int* in_sizes, int n_in,
                              void* d_out, int out_size, void* d_ws, size_t ws_size,
                              hipStream_t stream) {
    const float* x      = (const float*)d_in[0];
    const int*   eidx   = (const int*)d_in[1];
    const int*   eattr  = (const int*)d_in[2];
    const float* W1     = (const float*)d_in[3];
    const float* b1     = (const float*)d_in[4];
    const float* ebond1 = (const float*)d_in[5];
    const float* edir1  = (const float*)d_in[6];
    const float* W2     = (const float*)d_in[7];
    const float* b2     = (const float*)d_in[8];
    const float* ebond2 = (const float*)d_in[9];
    const float* edir2  = (const float*)d_in[10];

    const int N = in_sizes[0] / 64;
    const int E = in_sizes[1] / 2;
    const int* src = eidx;
    const int* dst = eidx + E;
    float* out = (float*)d_out;
    const int NB2 = (N + 255) >> 8;         // 256-node buckets
    const int SCB = (E + CHUNK - 1) / CHUNK;

    // Workspace (~60 MB of 256 MiB)
    char* w = (char*)d_ws;
    size_t Na = ((size_t)N * 4 + 255) & ~(size_t)255;
    float2* dsc    = (float2*)w;           w += 2 * Na;   // layer1 {dis, scale1}
    float2* dsc2   = (float2*)w;           w += 2 * Na;   // layer2 {dis, scale2}
    int2*  rc      = (int2*)w;             w += 2 * Na;   // {row_ptr, cnt}
    int*   gcur    = (int*)w;              w += 2 * NBINS * 4;
    unsigned int* payD   = (unsigned int*)w;   w += (size_t)NBINS * BCAP * 4;   // 8 MB
    unsigned int* sorted = (unsigned int*)w;   w += (size_t)NBINS * BCAP * 4;   // 8 MB
    unsigned char* payS  = (unsigned char*)w;  w += (size_t)NBINS * BCAP;       // 2 MB
    unsigned short* Hb1  = (unsigned short*)w; w += (size_t)N * 64 * 2;         // 12.8 MB
    unsigned char*  Hq1  = (unsigned char*)w;  w += ((size_t)N * 64 + 255) & ~(size_t)255;
    unsigned short* Hb2  = (unsigned short*)w; w += (size_t)N * 64 * 2;         // 12.8 MB
    unsigned char*  Hq2  = (unsigned char*)w;  w += ((size_t)N * 64 + 255) & ~(size_t)255;
    int* gcurS = gcur;
    int* gcurD = gcur + NBINS;

    const int gT   = (N + 63) / 64;   // gemm/fused tiles
    const int gN32 = (N + 31) / 32;   // aggregate: 32 nodes/block

    // all gemm1 tiles ride in K0+K1 (gemm1 depends only on x; must be done before K3)
    const int t0 = min(gT, 512);
    const int t1 = gT - t0;

    zero_gemm_kernel<<<1 + t0, THREADS, 0, stream>>>(gcur, 2 * NBINS, x, W1, b1, Hb1, Hq1,
                                                     dsc, N, 0);
    scatter_kernel<<<SCB + t1, THREADS, 0, stream>>>(src, dst, eattr, gcurS, gcurD, payS,
                                                     payD, E, SCB, x, W1, b1, Hb1, Hq1,
                                                     dsc, N, t0);
    build_kernel<<<2 * NB2, THREADS, 0, stream>>>(payS, payD, gcurS, gcurD, sorted,
                                                  rc, NB2, dsc, N);

    // fused: aggregate layer 1 (ReLU,bf16 in LDS) -> gemm2 -> Hb2/Hq2/dsc2
    agg_gemm_kernel<<<gT, THREADS, 0, stream>>>(Hb1, Hq1, dsc, ebond1, edir1, rc, sorted,
                                                W2, b2, Hb2, Hq2, dsc2, N);

    // layer 2 aggregate -> fp32 out
    aggregate_kernel<<<gN32, THREADS, 0, stream>>>(Hb2, Hq2, dsc2, ebond2, edir2, rc,
                                                   sorted, out, N);
}